// Round 14
// baseline (3093.554 us; speedup 1.0000x reference)
//
#include <hip/hip_runtime.h>

#define Bsz 128
#define Tlen 1024
#define Din 256
#define Hdim 512

#define NBG 8    // batch groups (16 rows each)
#define NCG 16   // col groups (32 h-cols each)
#define NWG 64   // 16 cg x 4 pairs; WG serves bgA=2p, bgB=2p+1

typedef __attribute__((ext_vector_type(8))) short short8;
typedef __attribute__((ext_vector_type(4))) float f32x4;
typedef __attribute__((ext_vector_type(4))) unsigned short ushort4_;
typedef __attribute__((ext_vector_type(4))) unsigned int uint4v;

// tagged h exchange: u32 = (bf16<<16) | tag ; [2 parity][NBG][16 rows][512 cols]
#define HBT_BYTES ((size_t)2 * NBG * 16 * Hdim * 4)  // 524,288
#define HT_OFF ((size_t)524288)
#define XB_OFF ((size_t)786432)
#define XB_BYTES ((size_t)Bsz * Tlen * Din * 2)  // 67,108,864 (x as bf16)

__device__ inline unsigned short f2bf(float f) {
    unsigned int u = __builtin_bit_cast(unsigned int, f);
    unsigned int lsb = (u >> 16) & 1u;
    u += 0x7fffu + lsb;  // RNE
    return (unsigned short)(u >> 16);
}
__device__ inline float sigm_f(float x) { return 1.f / (1.f + __expf(-x)); }
__device__ inline float tanh_f(float x) { return 1.f - 2.f / (__expf(2.f * x) + 1.f); }

__device__ __forceinline__ bool chunk_ok(uint4v v, unsigned want) {
    unsigned m =
        ((v[0] ^ want) | (v[1] ^ want) | (v[2] ^ want) | (v[3] ^ want)) & 0xFFFFu;
    return m == 0;
}
__device__ __forceinline__ void chunk_to_lds(uint4v v, int c, unsigned char* h_lds) {
    int row = c >> 7;
    unsigned lo = (v[0] >> 16) | (v[1] & 0xFFFF0000u);
    unsigned hi = (v[2] >> 16) | (v[3] & 0xFFFF0000u);
    int a = ((row << 10) + ((c & 127) << 3)) ^ ((row & 7) << 4);
    *(unsigned long long*)(h_lds + a) =
        (unsigned long long)lo | ((unsigned long long)hi << 32);
}

// caller has already done the counted vmcnt for the first-issued sweep
__device__ __forceinline__ void validate_fill(uint4v& r0, uint4v& r1, uint4v& r2,
                                              uint4v& r3, const unsigned int* p0,
                                              const unsigned int* p1,
                                              const unsigned int* p2,
                                              const unsigned int* p3, unsigned want,
                                              int tid, unsigned char* h_lds) {
    unsigned need = 0;
    if (chunk_ok(r0, want)) chunk_to_lds(r0, tid, h_lds); else need |= 1u;
    if (chunk_ok(r1, want)) chunk_to_lds(r1, tid + 512, h_lds); else need |= 2u;
    if (chunk_ok(r2, want)) chunk_to_lds(r2, tid + 1024, h_lds); else need |= 4u;
    if (chunk_ok(r3, want)) chunk_to_lds(r3, tid + 1536, h_lds); else need |= 8u;
    int rounds = 0;
    while (need && ++rounds < (1 << 15)) {
        if (rounds > 8) __builtin_amdgcn_s_sleep(1);
        if (need & 1u)
            asm volatile("global_load_dwordx4 %0, %1, off sc0 sc1"
                         : "=&v"(r0) : "v"(p0) : "memory");
        if (need & 2u)
            asm volatile("global_load_dwordx4 %0, %1, off sc0 sc1"
                         : "=&v"(r1) : "v"(p1) : "memory");
        if (need & 4u)
            asm volatile("global_load_dwordx4 %0, %1, off sc0 sc1"
                         : "=&v"(r2) : "v"(p2) : "memory");
        if (need & 8u)
            asm volatile("global_load_dwordx4 %0, %1, off sc0 sc1"
                         : "=&v"(r3) : "v"(p3) : "memory");
        asm volatile("s_waitcnt vmcnt(0)" ::: "memory");
        __builtin_amdgcn_sched_barrier(0);
        if ((need & 1u) && chunk_ok(r0, want)) { chunk_to_lds(r0, tid, h_lds); need &= ~1u; }
        if ((need & 2u) && chunk_ok(r1, want)) { chunk_to_lds(r1, tid + 512, h_lds); need &= ~2u; }
        if ((need & 4u) && chunk_ok(r2, want)) { chunk_to_lds(r2, tid + 1024, h_lds); need &= ~4u; }
        if ((need & 8u) && chunk_ok(r3, want)) { chunk_to_lds(r3, tid + 1536, h_lds); need &= ~8u; }
    }
}

#define SWEEP_ISSUE(r0, r1, r2, r3, p0, p1, p2, p3)                 \
    asm volatile("global_load_dwordx4 %0, %4, off sc0 sc1\n\t"      \
                 "global_load_dwordx4 %1, %5, off sc0 sc1\n\t"      \
                 "global_load_dwordx4 %2, %6, off sc0 sc1\n\t"      \
                 "global_load_dwordx4 %3, %7, off sc0 sc1"          \
                 : "=&v"(r0), "=&v"(r1), "=&v"(r2), "=&v"(r3)       \
                 : "v"(p0), "v"(p1), "v"(p2), "v"(p3)               \
                 : "memory")

// ---- phase 0 (optional): x fp32 -> bf16, natural [B][T][D] layout ----
__global__ __launch_bounds__(256) void xconv(const float* __restrict__ x,
                                             unsigned short* __restrict__ xb) {
    const size_t nthreads = (size_t)2048 * 256;
#pragma unroll
    for (int it = 0; it < 8; ++it) {
        size_t base = ((size_t)blockIdx.x * 256 + threadIdx.x + it * nthreads) * 8;
        float4 a = *(const float4*)(x + base);
        float4 b = *(const float4*)(x + base + 4);
        short8 o;
        o[0] = (short)f2bf(a.x); o[1] = (short)f2bf(a.y);
        o[2] = (short)f2bf(a.z); o[3] = (short)f2bf(a.w);
        o[4] = (short)f2bf(b.x); o[5] = (short)f2bf(b.y);
        o[6] = (short)f2bf(b.z); o[7] = (short)f2bf(b.w);
        *(short8*)(xb + base) = o;
    }
}

// ================= paired persistent recurrence: 64 WGs x 512 thr ==================
template <bool XB>
__global__ __launch_bounds__(512, 1) void lstm_pair(
    const float* __restrict__ x, const unsigned short* __restrict__ xb,
    const float* __restrict__ Wih, const float* __restrict__ Whh,
    const float* __restrict__ bih, const float* __restrict__ bhh,
    unsigned int* __restrict__ hbt, float* __restrict__ hT) {
    __shared__ unsigned char h_lds[16 * 1024];   // shared by A/B sub-steps
    __shared__ unsigned char xA_lds[2 * 8192];   // dbuf x for bgA
    __shared__ unsigned char xB_lds[2 * 8192];   // dbuf x for bgB
    __shared__ float gates_w[8][16 * 17];

    const int tid = threadIdx.x;
    const int wg = blockIdx.x;
    const int cg = wg >> 2;          // 0..15
    const int pr = wg & 3;           // 0..3
    const int bgA = pr * 2, bgB = pr * 2 + 1;
    const int growA = bgA * 16, growB = bgB * 16;
    const int lane = tid & 63;
    const int w = tid >> 6;
    const int n15 = lane & 15;
    const int k8 = lane >> 4;
    const int gc = n15 & 3;
    const int gsel = n15 >> 2;
    const int myb = k8 * 4 + gsel;
    const int mycol = cg * 32 + w * 4 + gc;
    const int R = (n15 >> 2) * Hdim + mycol;

    // ---- weights: shared across both batch groups ----
    short8 whh[16], wihh[8];
    {
        const float* wr = Whh + (size_t)R * Hdim;
#pragma unroll
        for (int kc = 0; kc < 16; kc++) {
            const float* p = wr + kc * 32 + k8 * 8;
            short8 f;
#pragma unroll
            for (int e = 0; e < 8; e++) f[e] = (short)f2bf(p[e]);
            whh[kc] = f;
        }
        const float* wr2 = Wih + (size_t)R * Din;
#pragma unroll
        for (int kc = 0; kc < 8; kc++) {
            const float* p = wr2 + kc * 32 + k8 * 8;
            short8 f;
#pragma unroll
            for (int e = 0; e < 8; e++) f[e] = (short)f2bf(p[e]);
            wihh[kc] = f;
        }
    }
    float bias4[4];
#pragma unroll
    for (int g = 0; g < 4; g++) bias4[g] = bih[g * Hdim + mycol] + bhh[g * Hdim + mycol];

    // ---- x staging state ----
    const int xrow = tid >> 5, xc8 = tid & 31;
    const int xa = ((xrow << 9) + (xc8 << 4)) ^ ((xrow & 7) << 4);
    short8 xrA8, xrB8;
    float4 xfA, xfB;  // fallback holds 4 floats -> 8B; need 16B: use 2
    float4 xfA2, xfB2;

    if (XB) {
        const unsigned short* xpA = xb + (size_t)(growA + xrow) * Tlen * Din;
        const unsigned short* xpB = xb + (size_t)(growB + xrow) * Tlen * Din;
        *(short8*)(xA_lds + xa) = *(const short8*)(xpA + xc8 * 8);
        *(short8*)(xB_lds + xa) = *(const short8*)(xpB + xc8 * 8);
        xrA8 = *(const short8*)(xpA + Din + xc8 * 8);
        xrB8 = *(const short8*)(xpB + Din + xc8 * 8);
    } else {
        const float* xpA = x + (size_t)(growA + xrow) * Tlen * Din;
        const float* xpB = x + (size_t)(growB + xrow) * Tlen * Din;
        float4 a0 = *(const float4*)(xpA + xc8 * 8);
        float4 a1 = *(const float4*)(xpA + xc8 * 8 + 4);
        float4 b0 = *(const float4*)(xpB + xc8 * 8);
        float4 b1 = *(const float4*)(xpB + xc8 * 8 + 4);
        short8 oa, ob;
        oa[0]=(short)f2bf(a0.x); oa[1]=(short)f2bf(a0.y); oa[2]=(short)f2bf(a0.z); oa[3]=(short)f2bf(a0.w);
        oa[4]=(short)f2bf(a1.x); oa[5]=(short)f2bf(a1.y); oa[6]=(short)f2bf(a1.z); oa[7]=(short)f2bf(a1.w);
        ob[0]=(short)f2bf(b0.x); ob[1]=(short)f2bf(b0.y); ob[2]=(short)f2bf(b0.z); ob[3]=(short)f2bf(b0.w);
        ob[4]=(short)f2bf(b1.x); ob[5]=(short)f2bf(b1.y); ob[6]=(short)f2bf(b1.z); ob[7]=(short)f2bf(b1.w);
        *(short8*)(xA_lds + xa) = oa;
        *(short8*)(xB_lds + xa) = ob;
        xfA = *(const float4*)(xpA + Din + xc8 * 8);
        xfA2 = *(const float4*)(xpA + Din + xc8 * 8 + 4);
        xfB = *(const float4*)(xpB + Din + xc8 * 8);
        xfB2 = *(const float4*)(xpB + Din + xc8 * 8 + 4);
    }
    __syncthreads();

    float cA = 0.f, hAv = 0.f, cB = 0.f, hBv = 0.f;
    uint4v sA0, sA1, sA2, sA3, sB0, sB1, sB2, sB3;

    for (int t = 0; t < Tlen; ++t) {
        const size_t pbA = ((size_t)(t & 1) * NBG + bgA) * 8192;
        const size_t pbB = ((size_t)(t & 1) * NBG + bgB) * 8192;
        const unsigned int* pA0 = hbt + pbA + (size_t)tid * 4;
        const unsigned int* pA1 = hbt + pbA + (size_t)(tid + 512) * 4;
        const unsigned int* pA2 = hbt + pbA + (size_t)(tid + 1024) * 4;
        const unsigned int* pA3 = hbt + pbA + (size_t)(tid + 1536) * 4;
        const unsigned int* pB0 = hbt + pbB + (size_t)tid * 4;
        const unsigned int* pB1 = hbt + pbB + (size_t)(tid + 512) * 4;
        const unsigned int* pB2 = hbt + pbB + (size_t)(tid + 1024) * 4;
        const unsigned int* pB3 = hbt + pbB + (size_t)(tid + 1536) * 4;

        // ============ sub-step A ============
        if (t > 0) {
            // sA issued mid-[C_B] last iter; pubB was newest VMEM op
            asm volatile("s_waitcnt vmcnt(1)" ::: "memory");
            __builtin_amdgcn_sched_barrier(0);
            validate_fill(sA0, sA1, sA2, sA3, pA0, pA1, pA2, pA3, (unsigned)t, tid,
                          h_lds);
        } else {
#pragma unroll
            for (int i = 0; i < 4; i++) {
                int c = tid + i * 512;
                int row = c >> 7;
                int a = ((row << 10) + ((c & 127) << 3)) ^ ((row & 7) << 4);
                *(unsigned long long*)(h_lds + a) = 0ULL;
            }
        }
        asm volatile("s_waitcnt lgkmcnt(0)" ::: "memory");
        __builtin_amdgcn_s_barrier();
        __builtin_amdgcn_sched_barrier(0);

        // [C_A]
        {
            unsigned char* xh = xA_lds + (t & 1) * 8192;
            f32x4 acc0 = {0.f, 0.f, 0.f, 0.f}, acc1 = {0.f, 0.f, 0.f, 0.f};
#pragma unroll
            for (int kc = 0; kc < 8; kc++) {
                int a = (((n15 << 9) + (kc << 6) + (k8 << 4)) ^ ((n15 & 7) << 4));
                short8 xv = *(const short8*)(xh + a);
                if (kc & 1)
                    acc1 = __builtin_amdgcn_mfma_f32_16x16x32_bf16(xv, wihh[kc], acc1, 0, 0, 0);
                else
                    acc0 = __builtin_amdgcn_mfma_f32_16x16x32_bf16(xv, wihh[kc], acc0, 0, 0, 0);
            }
            // mid-phase: issue B's sweep for tag t (published iter t-1 [C_B])
            __builtin_amdgcn_sched_barrier(0);
            if (t > 0) SWEEP_ISSUE(sB0, sB1, sB2, sB3, pB0, pB1, pB2, pB3);
            __builtin_amdgcn_sched_barrier(0);
#pragma unroll
            for (int kc = 0; kc < 16; kc++) {
                short8 a = *(const short8*)(h_lds + (((n15 << 10) + (kc << 6) + (k8 << 4)) ^
                                                    ((n15 & 7) << 4)));
                if (kc & 1)
                    acc1 = __builtin_amdgcn_mfma_f32_16x16x32_bf16(a, whh[kc], acc1, 0, 0, 0);
                else
                    acc0 = __builtin_amdgcn_mfma_f32_16x16x32_bf16(a, whh[kc], acc0, 0, 0, 0);
            }
            // stage xA(t+1); prefetch xA(t+2)
            if (t + 1 < Tlen) {
                unsigned char* xdst = xA_lds + ((t + 1) & 1) * 8192;
                if (XB) {
                    *(short8*)(xdst + xa) = xrA8;
                } else {
                    short8 o;
                    o[0]=(short)f2bf(xfA.x); o[1]=(short)f2bf(xfA.y); o[2]=(short)f2bf(xfA.z); o[3]=(short)f2bf(xfA.w);
                    o[4]=(short)f2bf(xfA2.x); o[5]=(short)f2bf(xfA2.y); o[6]=(short)f2bf(xfA2.z); o[7]=(short)f2bf(xfA2.w);
                    *(short8*)(xdst + xa) = o;
                }
            }
            if (t + 2 < Tlen) {
                if (XB) {
                    xrA8 = *(const short8*)(xb + ((size_t)(growA + xrow) * Tlen + (t + 2)) * Din + xc8 * 8);
                } else {
                    const float* s = x + ((size_t)(growA + xrow) * Tlen + (t + 2)) * Din + xc8 * 8;
                    xfA = *(const float4*)s;
                    xfA2 = *(const float4*)(s + 4);
                }
            }
            // gates -> cell A -> publish (LAST VMEM op of sub-step)
            float* gt = gates_w[w];
#pragma unroll
            for (int j2 = 0; j2 < 4; j2++) gt[(k8 * 4 + j2) * 17 + n15] = acc0[j2] + acc1[j2];
            float pre[4];
#pragma unroll
            for (int g = 0; g < 4; g++) pre[g] = gt[myb * 17 + g * 4 + gc] + bias4[g];
            float ig = sigm_f(pre[0]);
            float fg = sigm_f(pre[1]);
            float gg = tanh_f(pre[2]);
            float og = sigm_f(pre[3]);
            cA = fg * cA + ig * gg;
            hAv = og * tanh_f(cA);
            if (t + 1 < Tlen) {
                unsigned int word = ((unsigned int)f2bf(hAv) << 16) | (unsigned)(t + 1);
                unsigned int* dst = hbt + ((size_t)((t + 1) & 1) * NBG + bgA) * 8192 +
                                    (size_t)myb * Hdim + mycol;
                __builtin_amdgcn_sched_barrier(0);
                asm volatile("global_store_dword %0, %1, off sc0 sc1" ::"v"(dst),
                             "v"(word)
                             : "memory");
                __builtin_amdgcn_sched_barrier(0);
            }
        }
        asm volatile("s_waitcnt lgkmcnt(0)" ::: "memory");
        __builtin_amdgcn_s_barrier();
        __builtin_amdgcn_sched_barrier(0);

        // ============ sub-step B ============
        if (t > 0) {
            if (t + 1 < Tlen)
                asm volatile("s_waitcnt vmcnt(1)" ::: "memory");  // pubA newest
            else
                asm volatile("s_waitcnt vmcnt(0)" ::: "memory");  // no pubA at 1023
            __builtin_amdgcn_sched_barrier(0);
            validate_fill(sB0, sB1, sB2, sB3, pB0, pB1, pB2, pB3, (unsigned)t, tid,
                          h_lds);
        }
        // t==0: h_lds still zero from sub-A
        asm volatile("s_waitcnt lgkmcnt(0)" ::: "memory");
        __builtin_amdgcn_s_barrier();
        __builtin_amdgcn_sched_barrier(0);

        // [C_B]
        {
            unsigned char* xh = xB_lds + (t & 1) * 8192;
            f32x4 acc0 = {0.f, 0.f, 0.f, 0.f}, acc1 = {0.f, 0.f, 0.f, 0.f};
#pragma unroll
            for (int kc = 0; kc < 8; kc++) {
                int a = (((n15 << 9) + (kc << 6) + (k8 << 4)) ^ ((n15 & 7) << 4));
                short8 xv = *(const short8*)(xh + a);
                if (kc & 1)
                    acc1 = __builtin_amdgcn_mfma_f32_16x16x32_bf16(xv, wihh[kc], acc1, 0, 0, 0);
                else
                    acc0 = __builtin_amdgcn_mfma_f32_16x16x32_bf16(xv, wihh[kc], acc0, 0, 0, 0);
            }
            // mid-phase: issue A's sweep for tag t+1 (published this iter [C_A])
            __builtin_amdgcn_sched_barrier(0);
            if (t + 1 < Tlen) {
                const size_t nbA = ((size_t)((t + 1) & 1) * NBG + bgA) * 8192;
                SWEEP_ISSUE(sA0, sA1, sA2, sA3, hbt + nbA + (size_t)tid * 4,
                            hbt + nbA + (size_t)(tid + 512) * 4,
                            hbt + nbA + (size_t)(tid + 1024) * 4,
                            hbt + nbA + (size_t)(tid + 1536) * 4);
            }
            __builtin_amdgcn_sched_barrier(0);
#pragma unroll
            for (int kc = 0; kc < 16; kc++) {
                short8 a = *(const short8*)(h_lds + (((n15 << 10) + (kc << 6) + (k8 << 4)) ^
                                                    ((n15 & 7) << 4)));
                if (kc & 1)
                    acc1 = __builtin_amdgcn_mfma_f32_16x16x32_bf16(a, whh[kc], acc1, 0, 0, 0);
                else
                    acc0 = __builtin_amdgcn_mfma_f32_16x16x32_bf16(a, whh[kc], acc0, 0, 0, 0);
            }
            // stage xB(t+1); prefetch xB(t+2)
            if (t + 1 < Tlen) {
                unsigned char* xdst = xB_lds + ((t + 1) & 1) * 8192;
                if (XB) {
                    *(short8*)(xdst + xa) = xrB8;
                } else {
                    short8 o;
                    o[0]=(short)f2bf(xfB.x); o[1]=(short)f2bf(xfB.y); o[2]=(short)f2bf(xfB.z); o[3]=(short)f2bf(xfB.w);
                    o[4]=(short)f2bf(xfB2.x); o[5]=(short)f2bf(xfB2.y); o[6]=(short)f2bf(xfB2.z); o[7]=(short)f2bf(xfB2.w);
                    *(short8*)(xdst + xa) = o;
                }
            }
            if (t + 2 < Tlen) {
                if (XB) {
                    xrB8 = *(const short8*)(xb + ((size_t)(growB + xrow) * Tlen + (t + 2)) * Din + xc8 * 8);
                } else {
                    const float* s = x + ((size_t)(growB + xrow) * Tlen + (t + 2)) * Din + xc8 * 8;
                    xfB = *(const float4*)s;
                    xfB2 = *(const float4*)(s + 4);
                }
            }
            // gates -> cell B -> publish (last VMEM op)
            float* gt = gates_w[w];
#pragma unroll
            for (int j2 = 0; j2 < 4; j2++) gt[(k8 * 4 + j2) * 17 + n15] = acc0[j2] + acc1[j2];
            float pre[4];
#pragma unroll
            for (int g = 0; g < 4; g++) pre[g] = gt[myb * 17 + g * 4 + gc] + bias4[g];
            float ig = sigm_f(pre[0]);
            float fg = sigm_f(pre[1]);
            float gg = tanh_f(pre[2]);
            float og = sigm_f(pre[3]);
            cB = fg * cB + ig * gg;
            hBv = og * tanh_f(cB);
            if (t + 1 < Tlen) {
                unsigned int word = ((unsigned int)f2bf(hBv) << 16) | (unsigned)(t + 1);
                unsigned int* dst = hbt + ((size_t)((t + 1) & 1) * NBG + bgB) * 8192 +
                                    (size_t)myb * Hdim + mycol;
                __builtin_amdgcn_sched_barrier(0);
                asm volatile("global_store_dword %0, %1, off sc0 sc1" ::"v"(dst),
                             "v"(word)
                             : "memory");
                __builtin_amdgcn_sched_barrier(0);
            }
        }
        asm volatile("s_waitcnt lgkmcnt(0)" ::: "memory");
        __builtin_amdgcn_s_barrier();
        __builtin_amdgcn_sched_barrier(0);
    }

    hT[(size_t)(growA + myb) * Hdim + mycol] = hAv;
    hT[(size_t)(growB + myb) * Hdim + mycol] = hBv;
}

__global__ __launch_bounds__(256) void out_proj(const float* __restrict__ hT,
                                                const float* __restrict__ Wout,
                                                const float* __restrict__ bout,
                                                float* __restrict__ out) {
    __shared__ float h_s[16 * 512];
    __shared__ float w_s[64 * 69];
    const int tid = threadIdx.x;
    const int bt = blockIdx.x >> 2;
    const int ot = blockIdx.x & 3;
#pragma unroll
    for (int i = 0; i < 8; i++) {
        int cidx = tid + i * 256;
        int row = cidx >> 7;
        int c4 = cidx & 127;
        *(float4*)(&h_s[row * 512 + c4 * 4]) =
            *(const float4*)(hT + (size_t)(bt * 16 + row) * 512 + c4 * 4);
    }
    const int o = tid & 63;
    const int bq = tid >> 6;
    float acc[4] = {0.f, 0.f, 0.f, 0.f};
    for (int kc = 0; kc < 8; kc++) {
        __syncthreads();
#pragma unroll
        for (int i = 0; i < 4; i++) {
            int cidx = tid + i * 256;
            int row = cidx >> 4;
            int c4 = cidx & 15;
            float4 v = *(const float4*)(Wout + (size_t)(ot * 64 + row) * 512 + kc * 64 +
                                        c4 * 4);
            float* dst = &w_s[row * 69 + c4 * 4];
            dst[0] = v.x;
            dst[1] = v.y;
            dst[2] = v.z;
            dst[3] = v.w;
        }
        __syncthreads();
#pragma unroll 16
        for (int k = 0; k < 64; k++) {
            float wv = w_s[o * 69 + k];
#pragma unroll
            for (int bi = 0; bi < 4; bi++)
                acc[bi] += h_s[(bq * 4 + bi) * 512 + kc * 64 + k] * wv;
        }
    }
    float bo = bout[ot * 64 + o];
#pragma unroll
    for (int bi = 0; bi < 4; bi++)
        out[(size_t)(bt * 16 + bq * 4 + bi) * 256 + ot * 64 + o] = acc[bi] + bo;
}

extern "C" void kernel_launch(void* const* d_in, const int* in_sizes, int n_in,
                              void* d_out, int out_size, void* d_ws, size_t ws_size,
                              hipStream_t stream) {
    const float* x = (const float*)d_in[0];
    const float* Wih = (const float*)d_in[1];
    const float* Whh = (const float*)d_in[2];
    const float* bih = (const float*)d_in[3];
    const float* bhh = (const float*)d_in[4];
    const float* Wout = (const float*)d_in[5];
    const float* bout = (const float*)d_in[6];
    float* out = (float*)d_out;

    char* ws = (char*)d_ws;
    unsigned int* hbt = (unsigned int*)ws;
    float* hT = (float*)(ws + HT_OFF);
    unsigned short* xbuf = (unsigned short*)(ws + XB_OFF);

    hipMemsetAsync(hbt, 0, HBT_BYTES, stream);  // clear tags: replay determinism
    if (ws_size >= XB_OFF + XB_BYTES) {
        xconv<<<dim3(2048), dim3(256), 0, stream>>>(x, xbuf);
        lstm_pair<true><<<dim3(NWG), dim3(512), 0, stream>>>(x, xbuf, Wih, Whh, bih,
                                                             bhh, hbt, hT);
    } else {
        lstm_pair<false><<<dim3(NWG), dim3(512), 0, stream>>>(
            x, (const unsigned short*)nullptr, Wih, Whh, bih, bhh, hbt, hT);
    }
    out_proj<<<dim3(32), dim3(256), 0, stream>>>(hT, Wout, bout, out);
}

// Round 16
// 2011.931 us; speedup vs baseline: 1.5376x; 1.5376x over previous
//
#include <hip/hip_runtime.h>

#define Bsz 128
#define Tlen 1024
#define Din 256
#define Hdim 512

#define NBG 8    // batch groups (16 rows each)
#define NCG 16   // col groups per bg (32 h-cols each, 512-thread WGs)

typedef __attribute__((ext_vector_type(8))) short short8;
typedef __attribute__((ext_vector_type(4))) float f32x4;
typedef __attribute__((ext_vector_type(4))) unsigned short ushort4_;
typedef __attribute__((ext_vector_type(4))) unsigned int uint4v;

// tagged h exchange: u32 = (bf16<<16) | tag ; layout [2 parity][NBG][16 rows][512 cols]
#define HBT_BYTES ((size_t)2 * NBG * 16 * Hdim * 4)  // 524,288
#define HT_OFF ((size_t)524288)
#define XB_OFF ((size_t)786432)
#define XB_BYTES ((size_t)Bsz * Tlen * Din * 2)  // 67,108,864 (x as bf16)

__device__ inline unsigned short f2bf(float f) {
    unsigned int u = __builtin_bit_cast(unsigned int, f);
    unsigned int lsb = (u >> 16) & 1u;
    u += 0x7fffu + lsb;  // RNE
    return (unsigned short)(u >> 16);
}
__device__ inline float sigm_f(float x) { return 1.f / (1.f + __expf(-x)); }
__device__ inline float tanh_f(float x) { return 1.f - 2.f / (__expf(2.f * x) + 1.f); }

__device__ __forceinline__ bool chunk_ok(uint4v v, unsigned want) {
    unsigned m =
        ((v[0] ^ want) | (v[1] ^ want) | (v[2] ^ want) | (v[3] ^ want)) & 0xFFFFu;
    return m == 0;
}
__device__ __forceinline__ void chunk_to_lds(uint4v v, int c, unsigned char* h_lds) {
    int row = c >> 7;
    unsigned lo = (v[0] >> 16) | (v[1] & 0xFFFF0000u);
    unsigned hi = (v[2] >> 16) | (v[3] & 0xFFFF0000u);
    int a = ((row << 10) + ((c & 127) << 3)) ^ ((row & 7) << 4);
    *(unsigned long long*)(h_lds + a) =
        (unsigned long long)lo | ((unsigned long long)hi << 32);
}

// ---- phase 0 (optional): x fp32 -> bf16, natural [B][T][D] layout ----
__global__ __launch_bounds__(256) void xconv(const float* __restrict__ x,
                                             unsigned short* __restrict__ xb) {
    const size_t nthreads = (size_t)2048 * 256;
#pragma unroll
    for (int it = 0; it < 8; ++it) {
        size_t base =
            ((size_t)blockIdx.x * 256 + threadIdx.x + it * nthreads) * 8;
        float4 a = *(const float4*)(x + base);
        float4 b = *(const float4*)(x + base + 4);
        short8 o;
        o[0] = (short)f2bf(a.x); o[1] = (short)f2bf(a.y);
        o[2] = (short)f2bf(a.z); o[3] = (short)f2bf(a.w);
        o[4] = (short)f2bf(b.x); o[5] = (short)f2bf(b.y);
        o[6] = (short)f2bf(b.z); o[7] = (short)f2bf(b.w);
        *(short8*)(xb + base) = o;
    }
}

// ================= persistent recurrence (XB: x pre-converted to bf16) =============
template <bool XB>
__global__ __launch_bounds__(512, 1) void lstm_persist_t(
    const float* __restrict__ x, const unsigned short* __restrict__ xb,
    const float* __restrict__ Wih, const float* __restrict__ Whh,
    const float* __restrict__ bih, const float* __restrict__ bhh,
    unsigned int* __restrict__ hbt, float* __restrict__ hT) {
    __shared__ unsigned char h_lds[16 * 1024];   // [16][512] bf16, swizzled
    __shared__ unsigned char xh_lds[2 * 8192];   // dbuf [16][256] bf16, swizzled
    __shared__ float gates_w[8][16 * 17];        // per-wave [16 batch][16 gcol]

    const int tid = threadIdx.x;
    const int bid = blockIdx.x;
    const int bg = bid & 7;
    const int cg = bid >> 3;
    const int lane = tid & 63;
    const int w = tid >> 6;
    const int n15 = lane & 15;
    const int k8 = lane >> 4;
    const int grow = bg * 16;
    const int gc = n15 & 3;
    const int gsel = n15 >> 2;
    const int myb = k8 * 4 + gsel;
    const int mycol = cg * 32 + w * 4 + gc;
    const int R = (n15 >> 2) * Hdim + mycol;

    // ---- one-time: weight fragments (single bf16) ----
    short8 whh[16], wihh[8];
    {
        const float* wr = Whh + (size_t)R * Hdim;
#pragma unroll
        for (int kc = 0; kc < 16; kc++) {
            const float* p = wr + kc * 32 + k8 * 8;
            short8 f;
#pragma unroll
            for (int e = 0; e < 8; e++) f[e] = (short)f2bf(p[e]);
            whh[kc] = f;
        }
        const float* wr2 = Wih + (size_t)R * Din;
#pragma unroll
        for (int kc = 0; kc < 8; kc++) {
            const float* p = wr2 + kc * 32 + k8 * 8;
            short8 f;
#pragma unroll
            for (int e = 0; e < 8; e++) f[e] = (short)f2bf(p[e]);
            wihh[kc] = f;
        }
    }
    float bias4[4];
#pragma unroll
    for (int g = 0; g < 4; g++) bias4[g] = bih[g * Hdim + mycol] + bhh[g * Hdim + mycol];

    // ---- x staging state ----
    const int xrow = XB ? (tid >> 5) : 0;   // XB: 16B per thread per step
    const int xc8 = XB ? (tid & 31) : 0;
    short8 xr8;       // XB prefetch reg
    float4 xrf[2];    // !XB prefetch regs

    // prologue: stage x[0] -> buf0; prefetch x[1]
    if (XB) {
        const unsigned short* xrowp = xb + ((size_t)(grow + xrow) * Tlen) * Din;
        short8 v = *(const short8*)(xrowp + (size_t)0 * Din + xc8 * 8);
        int a = ((xrow << 9) + (xc8 << 4)) ^ ((xrow & 7) << 4);
        *(short8*)(xh_lds + a) = v;
        xr8 = *(const short8*)(xrowp + (size_t)1 * Din + xc8 * 8);
    } else {
        const float* xbase = x + (size_t)grow * (Tlen * Din);
#pragma unroll
        for (int i = 0; i < 2; i++) {
            int cidx = tid + i * 512;
            int row = cidx >> 6;
            int c4 = cidx & 63;
            float4 v = *(const float4*)(xbase + (size_t)row * (Tlen * Din) + c4 * 4);
            ushort4_ vh;
            vh[0] = f2bf(v.x); vh[1] = f2bf(v.y); vh[2] = f2bf(v.z); vh[3] = f2bf(v.w);
            int a = ((row << 9) + (c4 << 3)) ^ ((row & 7) << 4);
            *(ushort4_*)(xh_lds + a) = vh;
        }
#pragma unroll
        for (int i = 0; i < 2; i++) {
            int cidx = tid + i * 512;
            int row = cidx >> 6;
            int c4 = cidx & 63;
            xrf[i] = *(const float4*)(xbase + (size_t)row * (Tlen * Din) + Din + c4 * 4);
        }
    }
    __syncthreads();

    float c_reg = 0.f, h_last = 0.f;

    for (int t = 0; t < Tlen; ++t) {
        // (1) stage x(t+1) (regs -> LDS buf[(t+1)&1])
        if (t + 1 < Tlen) {
            unsigned char* xdst = xh_lds + ((t + 1) & 1) * 8192;
            if (XB) {
                int a = ((xrow << 9) + (xc8 << 4)) ^ ((xrow & 7) << 4);
                *(short8*)(xdst + a) = xr8;
            } else {
#pragma unroll
                for (int i = 0; i < 2; i++) {
                    int cidx = tid + i * 512;
                    int row = cidx >> 6;
                    int c4 = cidx & 63;
                    ushort4_ vh;
                    vh[0] = f2bf(xrf[i].x); vh[1] = f2bf(xrf[i].y);
                    vh[2] = f2bf(xrf[i].z); vh[3] = f2bf(xrf[i].w);
                    int a = ((row << 9) + (c4 << 3)) ^ ((row & 7) << 4);
                    *(ushort4_*)(xdst + a) = vh;
                }
            }
        }

        // (2) x-side MFMAs on buf[t&1] (8 single-bf16)
        unsigned char* xh = xh_lds + (t & 1) * 8192;
        f32x4 acc0 = {0.f, 0.f, 0.f, 0.f}, acc1 = {0.f, 0.f, 0.f, 0.f};
#pragma unroll
        for (int kc = 0; kc < 8; kc++) {
            int a = (((n15 << 9) + (kc << 6) + (k8 << 4)) ^ ((n15 & 7) << 4));
            short8 xv = *(const short8*)(xh + a);
            if (kc & 1)
                acc1 = __builtin_amdgcn_mfma_f32_16x16x32_bf16(xv, wihh[kc], acc1, 0, 0, 0);
            else
                acc0 = __builtin_amdgcn_mfma_f32_16x16x32_bf16(xv, wihh[kc], acc0, 0, 0, 0);
        }

        // (3) issue-LATE sweep + validate (first L3 access lands after peer publishes)
        if (t > 0) {
            const unsigned int* hb = hbt + ((size_t)(t & 1) * NBG + bg) * 8192;
            const unsigned int* p0 = hb + (size_t)tid * 4;
            const unsigned int* p1 = hb + (size_t)(tid + 512) * 4;
            const unsigned int* p2 = hb + (size_t)(tid + 1024) * 4;
            const unsigned int* p3 = hb + (size_t)(tid + 1536) * 4;
            uint4v r0, r1, r2, r3;
            asm volatile(
                "global_load_dwordx4 %0, %4, off sc0 sc1\n\t"
                "global_load_dwordx4 %1, %5, off sc0 sc1\n\t"
                "global_load_dwordx4 %2, %6, off sc0 sc1\n\t"
                "global_load_dwordx4 %3, %7, off sc0 sc1"
                : "=&v"(r0), "=&v"(r1), "=&v"(r2), "=&v"(r3)
                : "v"(p0), "v"(p1), "v"(p2), "v"(p3)
                : "memory");
            const unsigned want = (unsigned)t;
            asm volatile("s_waitcnt vmcnt(0)" ::: "memory");
            __builtin_amdgcn_sched_barrier(0);
            unsigned need = 0;
            if (chunk_ok(r0, want)) chunk_to_lds(r0, tid, h_lds); else need |= 1u;
            if (chunk_ok(r1, want)) chunk_to_lds(r1, tid + 512, h_lds); else need |= 2u;
            if (chunk_ok(r2, want)) chunk_to_lds(r2, tid + 1024, h_lds); else need |= 4u;
            if (chunk_ok(r3, want)) chunk_to_lds(r3, tid + 1536, h_lds); else need |= 8u;
            int rounds = 0;
            while (need && ++rounds < (1 << 14)) {
                if (rounds > 6) __builtin_amdgcn_s_sleep(1);
                if (need & 1u)
                    asm volatile("global_load_dwordx4 %0, %1, off sc0 sc1"
                                 : "=&v"(r0) : "v"(p0) : "memory");
                if (need & 2u)
                    asm volatile("global_load_dwordx4 %0, %1, off sc0 sc1"
                                 : "=&v"(r1) : "v"(p1) : "memory");
                if (need & 4u)
                    asm volatile("global_load_dwordx4 %0, %1, off sc0 sc1"
                                 : "=&v"(r2) : "v"(p2) : "memory");
                if (need & 8u)
                    asm volatile("global_load_dwordx4 %0, %1, off sc0 sc1"
                                 : "=&v"(r3) : "v"(p3) : "memory");
                asm volatile("s_waitcnt vmcnt(0)" ::: "memory");
                __builtin_amdgcn_sched_barrier(0);
                if ((need & 1u) && chunk_ok(r0, want)) { chunk_to_lds(r0, tid, h_lds); need &= ~1u; }
                if ((need & 2u) && chunk_ok(r1, want)) { chunk_to_lds(r1, tid + 512, h_lds); need &= ~2u; }
                if ((need & 4u) && chunk_ok(r2, want)) { chunk_to_lds(r2, tid + 1024, h_lds); need &= ~4u; }
                if ((need & 8u) && chunk_ok(r3, want)) { chunk_to_lds(r3, tid + 1536, h_lds); need &= ~8u; }
            }
        } else {
#pragma unroll
            for (int i = 0; i < 4; i++) {
                int c = tid + i * 512;
                int row = c >> 7;
                int a = ((row << 10) + ((c & 127) << 3)) ^ ((row & 7) << 4);
                *(unsigned long long*)(h_lds + a) = 0ULL;
            }
        }
        // barrier A: h_lds + x stage ready (LDS hazards only)
        asm volatile("s_waitcnt lgkmcnt(0)" ::: "memory");
        __builtin_amdgcn_s_barrier();
        __builtin_amdgcn_sched_barrier(0);

        // (4) h-side MFMAs
#pragma unroll
        for (int kc = 0; kc < 16; kc++) {
            short8 a = *(const short8*)(h_lds + (((n15 << 10) + (kc << 6) + (k8 << 4)) ^
                                                ((n15 & 7) << 4)));
            if (kc & 1)
                acc1 = __builtin_amdgcn_mfma_f32_16x16x32_bf16(a, whh[kc], acc1, 0, 0, 0);
            else
                acc0 = __builtin_amdgcn_mfma_f32_16x16x32_bf16(a, whh[kc], acc0, 0, 0, 0);
        }

        // (5) prefetch x(t+2) -> regs (in flight across barrier C)
        if (t + 2 < Tlen) {
            if (XB) {
                xr8 = *(const short8*)(xb + ((size_t)(grow + xrow) * Tlen + (t + 2)) * Din +
                                       xc8 * 8);
            } else {
                const float* xbase =
                    x + (size_t)grow * (Tlen * Din) + (size_t)(t + 2) * Din;
#pragma unroll
                for (int i = 0; i < 2; i++) {
                    int cidx = tid + i * 512;
                    int row = cidx >> 6;
                    int c4 = cidx & 63;
                    xrf[i] = *(const float4*)(xbase + (size_t)row * (Tlen * Din) + c4 * 4);
                }
            }
        }

        // (6) gates -> wave-private LDS; cell; fire-and-forget tagged publish
        float* gt = gates_w[w];
#pragma unroll
        for (int j2 = 0; j2 < 4; j2++) gt[(k8 * 4 + j2) * 17 + n15] = acc0[j2] + acc1[j2];
        {
            float pre[4];
#pragma unroll
            for (int g = 0; g < 4; g++) pre[g] = gt[myb * 17 + g * 4 + gc] + bias4[g];
            float ig = sigm_f(pre[0]);
            float fg = sigm_f(pre[1]);
            float gg = tanh_f(pre[2]);
            float og = sigm_f(pre[3]);
            c_reg = fg * c_reg + ig * gg;
            h_last = og * tanh_f(c_reg);
            unsigned int word = ((unsigned int)f2bf(h_last) << 16) | (unsigned)(t + 1);
            unsigned int* dst = hbt + ((size_t)((t + 1) & 1) * NBG + bg) * 8192 +
                                (size_t)myb * Hdim + mycol;
            __hip_atomic_store(dst, word, __ATOMIC_RELAXED, __HIP_MEMORY_SCOPE_AGENT);
        }
        // barrier C: LDS WAR separation only (publish + x prefetch stay in flight)
        asm volatile("s_waitcnt lgkmcnt(0)" ::: "memory");
        __builtin_amdgcn_s_barrier();
        __builtin_amdgcn_sched_barrier(0);
    }
    hT[(size_t)(grow + myb) * Hdim + mycol] = h_last;
}

__global__ __launch_bounds__(256) void out_proj(const float* __restrict__ hT,
                                                const float* __restrict__ Wout,
                                                const float* __restrict__ bout,
                                                float* __restrict__ out) {
    __shared__ float h_s[16 * 512];
    __shared__ float w_s[64 * 69];
    const int tid = threadIdx.x;
    const int bt = blockIdx.x >> 2;
    const int ot = blockIdx.x & 3;
#pragma unroll
    for (int i = 0; i < 8; i++) {
        int cidx = tid + i * 256;
        int row = cidx >> 7;
        int c4 = cidx & 127;
        *(float4*)(&h_s[row * 512 + c4 * 4]) =
            *(const float4*)(hT + (size_t)(bt * 16 + row) * 512 + c4 * 4);
    }
    const int o = tid & 63;
    const int bq = tid >> 6;
    float acc[4] = {0.f, 0.f, 0.f, 0.f};
    for (int kc = 0; kc < 8; kc++) {
        __syncthreads();
#pragma unroll
        for (int i = 0; i < 4; i++) {
            int cidx = tid + i * 256;
            int row = cidx >> 4;
            int c4 = cidx & 15;
            float4 v = *(const float4*)(Wout + (size_t)(ot * 64 + row) * 512 + kc * 64 +
                                        c4 * 4);
            float* dst = &w_s[row * 69 + c4 * 4];
            dst[0] = v.x;
            dst[1] = v.y;
            dst[2] = v.z;
            dst[3] = v.w;
        }
        __syncthreads();
#pragma unroll 16
        for (int k = 0; k < 64; k++) {
            float wv = w_s[o * 69 + k];
#pragma unroll
            for (int bi = 0; bi < 4; bi++)
                acc[bi] += h_s[(bq * 4 + bi) * 512 + kc * 64 + k] * wv;
        }
    }
    float bo = bout[ot * 64 + o];
#pragma unroll
    for (int bi = 0; bi < 4; bi++)
        out[(size_t)(bt * 16 + bq * 4 + bi) * 256 + ot * 64 + o] = acc[bi] + bo;
}

extern "C" void kernel_launch(void* const* d_in, const int* in_sizes, int n_in,
                              void* d_out, int out_size, void* d_ws, size_t ws_size,
                              hipStream_t stream) {
    const float* x = (const float*)d_in[0];
    const float* Wih = (const float*)d_in[1];
    const float* Whh = (const float*)d_in[2];
    const float* bih = (const float*)d_in[3];
    const float* bhh = (const float*)d_in[4];
    const float* Wout = (const float*)d_in[5];
    const float* bout = (const float*)d_in[6];
    float* out = (float*)d_out;

    char* ws = (char*)d_ws;
    unsigned int* hbt = (unsigned int*)ws;
    float* hT = (float*)(ws + HT_OFF);
    unsigned short* xbuf = (unsigned short*)(ws + XB_OFF);

    hipMemsetAsync(hbt, 0, HBT_BYTES, stream);  // clear tags: replay determinism
    if (ws_size >= XB_OFF + XB_BYTES) {
        xconv<<<dim3(2048), dim3(256), 0, stream>>>(x, xbuf);
        lstm_persist_t<true><<<dim3(NBG * NCG), dim3(512), 0, stream>>>(
            x, xbuf, Wih, Whh, bih, bhh, hbt, hT);
    } else {
        lstm_persist_t<false><<<dim3(NBG * NCG), dim3(512), 0, stream>>>(
            x, (const unsigned short*)nullptr, Wih, Whh, bih, bhh, hbt, hT);
    }
    out_proj<<<dim3(32), dim3(256), 0, stream>>>(hT, Wout, bout, out);
}